// Round 11
// baseline (489.251 us; speedup 1.0000x reference)
//
#include <hip/hip_runtime.h>

#define NN 100000
#define NE 1600000
#define NG 512
#define FIN 226
#define HD 128
#define BN_EPS 1e-5f
#define NBUK 196        // ceil(NN/512)
#define BCAP 10016      // per-bucket pair capacity (mean 8163)
#define BKB 391         // bucket blocks = ceil(NE/4096)
#define G1B 782         // gemm1 blocks = ceil(NN/128)

typedef __attribute__((ext_vector_type(8))) __bf16 bf16x8;
typedef __attribute__((ext_vector_type(8))) short short8;
typedef __attribute__((ext_vector_type(8))) unsigned short ushort8;
typedef __attribute__((ext_vector_type(4))) float f32x4;
typedef __attribute__((ext_vector_type(2))) float f32x2;

#define BC(x) __builtin_bit_cast(bf16x8, x)

__device__ inline unsigned short f2bf(float v) {
  unsigned u = __builtin_bit_cast(unsigned, v);
  return (unsigned short)((u + 0x7FFFu + ((u >> 16) & 1u)) >> 16);
}
__device__ inline float bf2f(unsigned short b) {
  return __builtin_bit_cast(float, (unsigned)b << 16);
}

// ---------------- merged weight/bias prep + workspace zeroing ----------------
struct PrepArgs {
  const float* W[9];
  const float* g[9];
  const float* rv[9];
  unsigned short* out[9];
  int k0[9];
  int K[9];
  const float* ba[4];
  const float* gg[4];
  const float* be[4];
  const float* rm[4];
  const float* rvv[4];
  float* bout;
};

__global__ __launch_bounds__(256) void k_prep(PrepArgs a, int* __restrict__ gcur,
                                              float* __restrict__ psum,
                                              int* __restrict__ done) {
  int id = blockIdx.x * 256 + threadIdx.x;
  if (id < 9 * 16384) {
    int chunk = id >> 14;
    int r = id & 16383;
    int kk = r >> 7;
    int n = r & 127;
    float s = a.g[chunk] ? a.g[chunk][n] * rsqrtf(a.rv[chunk][n] + BN_EPS) : 1.f;
    int kg = a.k0[chunk] + kk;
    float v = (kg < a.K[chunk]) ? a.W[chunk][(size_t)kg * HD + n] * s : 0.f;
    int idx = n * 128 + (kk ^ ((n & 7) << 3));
    a.out[chunk][idx] = f2bf(v);
  } else {
    int t = id - 9 * 16384;
    if (t < 512) {
      int l = t >> 7, c = t & 127;
      float s = a.gg[l][c] * rsqrtf(a.rvv[l][c] + BN_EPS);
      a.bout[l * 128 + c] = a.ba[l][c] * s + a.be[l][c] - a.rm[l][c] * s;
    } else if (t < 512 + 2 * NG) {
      psum[t - 512] = 0.f;
    } else if (t < 512 + 2 * NG + NBUK) {
      gcur[t - 512 - 2 * NG] = 0;
    } else if (t == 512 + 2 * NG + NBUK) {
      *done = 0;
    }
  }
}

// ---------------- fat kernel: bucket scatter (blocks 0..390) | GEMM1 (391..1172) ----
__global__ __launch_bounds__(256) void k_b1(const int* __restrict__ src,
                                            const int* __restrict__ dst,
                                            int* __restrict__ gcur,
                                            unsigned* __restrict__ pairs,
                                            const float* __restrict__ A,
                                            const unsigned short* __restrict__ Wz,
                                            unsigned short* __restrict__ out) {
  __shared__ __align__(16) char smem[32768];
  const int tid = threadIdx.x;
  if (blockIdx.x < BKB) {
    // ======== bucket body: dst staged in LDS; src re-read at scatter ========
    int* sd = (int*)smem;                       // 16 KB
    int* sh = (int*)(smem + 16384);             // NBUK
    int* sexcl = sh + NBUK;
    int* scur = sexcl + NBUK;
    int* sbase = scur + NBUK;
    int* wsum = sbase + NBUK;                   // 4
    const int i0 = blockIdx.x * 4096;
    #pragma unroll
    for (int j = 0; j < 16; ++j) {
      int e = i0 + j * 256 + tid;
      sd[j * 256 + tid] = (e < NE) ? __builtin_nontemporal_load(dst + e) : -1;
    }
    if (tid < NBUK) sh[tid] = 0;
    __syncthreads();
    #pragma unroll
    for (int j = 0; j < 16; ++j) {
      int d = sd[j * 256 + tid];
      if (d >= 0) atomicAdd(&sh[d >> 9], 1);
    }
    __syncthreads();
    {
      int v = (tid < NBUK) ? sh[tid] : 0;
      int lane = tid & 63, w = tid >> 6;
      int incl = v;
      #pragma unroll
      for (int o = 1; o < 64; o <<= 1) {
        int u = __shfl_up(incl, o);
        if (lane >= o) incl += u;
      }
      if (lane == 63) wsum[w] = incl;
      __syncthreads();
      int off = 0;
      for (int k = 0; k < w; ++k) off += wsum[k];
      if (tid < NBUK) {
        int ex = off + incl - v;
        sexcl[tid] = ex;
        scur[tid] = ex;
        sbase[tid] = (v > 0) ? atomicAdd(&gcur[tid], v) : 0;
      }
    }
    __syncthreads();
    #pragma unroll
    for (int j = 0; j < 16; ++j) {
      int d = sd[j * 256 + tid];
      if (d >= 0) {
        int b = d >> 9;
        int lp = atomicAdd(&scur[b], 1);
        int s = __builtin_nontemporal_load(src + i0 + j * 256 + tid);
        unsigned pk = ((unsigned)(d & 511) << 17) | (unsigned)s;
        pairs[(size_t)b * BCAP + sbase[b] + (lp - sexcl[b])] = pk;
      }
    }
  } else {
    // ======== GEMM1 body: f32 A hi+lo split @ bf16 W1a (2 chunks, K=226) ========
    unsigned short* sW = (unsigned short*)smem;  // 32 KB
    const int wv = tid >> 6, ln = tid & 63;
    const int l15 = ln & 15, l4 = ln >> 4;
    const int m0 = (blockIdx.x - BKB) * 128 + wv * 32;
    f32x4 acc[2][8] = {};
    const int sw = (l15 & 7) << 3;
    int kofs[4];
    #pragma unroll
    for (int ks = 0; ks < 4; ++ks) kofs[ks] = (((ks * 32 + l4 * 8) ^ sw)) + l15 * 128;

    for (int c = 0; c < 2; ++c) {
      {
        const ushort8* srcw = (const ushort8*)(Wz + (size_t)c * 16384);
        ushort8* dstw = (ushort8*)sW;
        #pragma unroll
        for (int i = 0; i < 8; ++i) dstw[tid + i * 256] = srcw[tid + i * 256];
      }
      __syncthreads();
      const int kc = c * 128;
      #pragma unroll
      for (int ks = 0; ks < 4; ++ks) {
        const int kbase = kc + ks * 32 + l4 * 8;
        const bool tail = (kc + ks * 32 + 32) > FIN;
        short8 ah[2], al[2];
        #pragma unroll
        for (int mf = 0; mf < 2; ++mf) {
          const int row = m0 + mf * 16 + l15;
          float v[8];
          if (row < NN && !tail) {
            const f32x2* ap = (const f32x2*)(A + (size_t)row * FIN + kbase);
            #pragma unroll
            for (int q = 0; q < 4; ++q) {
              f32x2 t = __builtin_nontemporal_load(ap + q);
              v[2 * q] = t[0]; v[2 * q + 1] = t[1];
            }
          } else if (row < NN) {
            #pragma unroll
            for (int j = 0; j < 8; ++j) {
              int k = kbase + j;
              v[j] = (k < FIN) ? A[(size_t)row * FIN + k] : 0.f;
            }
          } else {
            #pragma unroll
            for (int j = 0; j < 8; ++j) v[j] = 0.f;
          }
          #pragma unroll
          for (int j = 0; j < 8; ++j) {
            unsigned short hb = f2bf(v[j]);
            ah[mf][j] = (short)hb;
            al[mf][j] = (short)f2bf(v[j] - bf2f(hb));
          }
        }
        #pragma unroll
        for (int n = 0; n < 8; ++n) {
          short8 bh = *(const short8*)&sW[n * 2048 + kofs[ks]];
          #pragma unroll
          for (int mf = 0; mf < 2; ++mf) {
            acc[mf][n] = __builtin_amdgcn_mfma_f32_16x16x32_bf16(BC(ah[mf]), BC(bh), acc[mf][n], 0, 0, 0);
            acc[mf][n] = __builtin_amdgcn_mfma_f32_16x16x32_bf16(BC(al[mf]), BC(bh), acc[mf][n], 0, 0, 0);
          }
        }
      }
      __syncthreads();
    }
    #pragma unroll
    for (int mf = 0; mf < 2; ++mf) {
      #pragma unroll
      for (int n = 0; n < 8; ++n) {
        const int col = n * 16 + l15;
        #pragma unroll
        for (int r = 0; r < 4; ++r) {
          const int row = m0 + mf * 16 + l4 * 4 + r;
          if (row < NN) out[(size_t)row * HD + col] = f2bf(acc[mf][n][r]);
        }
      }
    }
  }
}

// pass 2 (512 threads): per-bucket local CSR; col_idx stored as row byte offset
__global__ __launch_bounds__(512) void k_pass2(const unsigned* __restrict__ pairs,
                                               const int* __restrict__ gcur,
                                               int* __restrict__ row_ptr,
                                               int* __restrict__ col_idx) {
  __shared__ unsigned spk[BCAP];
  __shared__ int h[512];
  __shared__ int cur[512];
  __shared__ int wsum[8];
  __shared__ int s_base;
  const int b = blockIdx.x;
  const int tid = threadIdx.x;
  const int lane = tid & 63, w = tid >> 6;
  {
    int v = (tid < NBUK) ? gcur[tid] : 0;
    int incl = v;
    #pragma unroll
    for (int o = 1; o < 64; o <<= 1) {
      int u = __shfl_up(incl, o);
      if (lane >= o) incl += u;
    }
    if (lane == 63) wsum[w] = incl;
    __syncthreads();
    int off = 0;
    for (int k = 0; k < w; ++k) off += wsum[k];
    if (tid == b) s_base = off + incl - v;
    if (b == 0 && tid == 0) row_ptr[NN] = NE;
  }
  const int cnt = gcur[b];
  __syncthreads();
  const int base = s_base;
  for (int i = tid; i < cnt; i += 512) spk[i] = pairs[(size_t)b * BCAP + i];
  h[tid] = 0;
  __syncthreads();
  for (int i = tid; i < cnt; i += 512) atomicAdd(&h[spk[i] >> 17], 1);
  __syncthreads();
  {
    int v = h[tid];
    int incl = v;
    #pragma unroll
    for (int o = 1; o < 64; o <<= 1) {
      int u = __shfl_up(incl, o);
      if (lane >= o) incl += u;
    }
    if (lane == 63) wsum[w] = incl;
    __syncthreads();
    int off = 0;
    for (int k = 0; k < w; ++k) off += wsum[k];
    int excl = off + incl - v;
    int node0 = b * 512 + tid;
    if (node0 < NN) row_ptr[node0] = base + excl;
    cur[tid] = excl;
  }
  __syncthreads();
  for (int i = tid; i < cnt; i += 512) {
    unsigned pk = spk[i];
    int dl = pk >> 17;
    int p = atomicAdd(&cur[dl], 1);
    col_idx[base + p] = (int)((pk & 0x1FFFFu) << 8);  // row byte offset (HD*2)
  }
}

// ---------------- aggregation (bf16): col_idx holds byte offsets ----------
__global__ __launch_bounds__(256) void k_agg(const unsigned short* __restrict__ y,
                                             const int* __restrict__ row_ptr,
                                             const int* __restrict__ col_idx,
                                             const float* __restrict__ bias,
                                             unsigned short* __restrict__ h) {
  const int node = blockIdx.x * 4 + (threadIdx.x >> 6);
  const int ln = threadIdx.x & 63;
  const int l15 = ln & 15, grp = ln >> 4;
  if (node >= NN) return;
  const char* yb = (const char*)y;
  const int lo = l15 * 16;
  float acc[8] = {};
  const int beg = row_ptr[node], end = row_ptr[node + 1];
  int e = beg;
  for (; e + 16 <= end; e += 16) {
    const int s0 = __builtin_nontemporal_load(col_idx + e + grp);
    const int s1 = __builtin_nontemporal_load(col_idx + e + 4 + grp);
    const int s2 = __builtin_nontemporal_load(col_idx + e + 8 + grp);
    const int s3 = __builtin_nontemporal_load(col_idx + e + 12 + grp);
    const ushort8 v0 = *(const ushort8*)(yb + s0 + lo);
    const ushort8 v1 = *(const ushort8*)(yb + s1 + lo);
    const ushort8 v2 = *(const ushort8*)(yb + s2 + lo);
    const ushort8 v3 = *(const ushort8*)(yb + s3 + lo);
    #pragma unroll
    for (int j = 0; j < 8; ++j)
      acc[j] += (bf2f((unsigned short)v0[j]) + bf2f((unsigned short)v1[j])) +
                (bf2f((unsigned short)v2[j]) + bf2f((unsigned short)v3[j]));
  }
  for (; e + 8 <= end; e += 8) {
    const int s0 = __builtin_nontemporal_load(col_idx + e + grp);
    const int s1 = __builtin_nontemporal_load(col_idx + e + 4 + grp);
    const ushort8 v0 = *(const ushort8*)(yb + s0 + lo);
    const ushort8 v1 = *(const ushort8*)(yb + s1 + lo);
    #pragma unroll
    for (int j = 0; j < 8; ++j)
      acc[j] += bf2f((unsigned short)v0[j]) + bf2f((unsigned short)v1[j]);
  }
  if (e + 4 <= end) {
    const int s0 = __builtin_nontemporal_load(col_idx + e + grp);
    const ushort8 v0 = *(const ushort8*)(yb + s0 + lo);
    #pragma unroll
    for (int j = 0; j < 8; ++j) acc[j] += bf2f((unsigned short)v0[j]);
    e += 4;
  }
  if (e + grp < end) {
    const int s0 = col_idx[e + grp];
    const ushort8 v0 = *(const ushort8*)(yb + s0 + lo);
    #pragma unroll
    for (int j = 0; j < 8; ++j) acc[j] += bf2f((unsigned short)v0[j]);
  }
  #pragma unroll
  for (int j = 0; j < 8; ++j) {
    acc[j] += __shfl_xor(acc[j], 16);
    acc[j] += __shfl_xor(acc[j], 32);
  }
  const ushort8 sv = *(const ushort8*)(y + (size_t)node * HD + l15 * 8);
  const f32x4* b4 = (const f32x4*)(bias + l15 * 8);
  const f32x4 b0 = b4[0], b1 = b4[1];
  ushort8 o;
  #pragma unroll
  for (int j = 0; j < 8; ++j) {
    const float bj = (j < 4) ? b0[j] : b1[j - 4];
    o[j] = (unsigned short)f2bf(fmaxf(acc[j] + bf2f((unsigned short)sv[j]) + bj, 0.f));
  }
  if (grp == 0) *(ushort8*)(h + (size_t)node * HD + l15 * 8) = o;
}

// ---------------- fused Wb+Wa GEMM (bf16 weights): Y = relu(H@Wb + bb) @ Wa ----------
__global__ __launch_bounds__(256) void k_fused(const unsigned short* __restrict__ H,
                                               const unsigned short* __restrict__ Wzb,
                                               const float* __restrict__ bb,
                                               const unsigned short* __restrict__ Wza,
                                               unsigned short* __restrict__ Yout) {
  __shared__ __align__(16) char smem[49152];
  unsigned short* sB = (unsigned short*)smem;            // 16 KB: Wb N-half
  unsigned short* sA2 = (unsigned short*)(smem + 16384); // 16 KB: Wa k-half
  unsigned short* sX = (unsigned short*)(smem + 32768);  // 16 KB: X half-tile swizzled
  const int tid = threadIdx.x;
  const int wv = tid >> 6, ln = tid & 63;
  const int l15 = ln & 15, l4 = ln >> 4;
  const int m0 = blockIdx.x * 128 + wv * 32;
  const int sw = (l15 & 7) << 3;
  f32x4 acc2[2][8] = {};

  short8 a[2][4];
  #pragma unroll
  for (int mf = 0; mf < 2; ++mf) {
    const int row = m0 + mf * 16 + l15;
    #pragma unroll
    for (int ks = 0; ks < 4; ++ks) {
      if (row < NN) a[mf][ks] = *(const short8*)(H + (size_t)row * HD + ks * 32 + l4 * 8);
      else a[mf][ks] = short8{0, 0, 0, 0, 0, 0, 0, 0};
    }
  }

  #pragma unroll 1
  for (int p = 0; p < 2; ++p) {
    {
      ushort8* d = (ushort8*)sB;
      const ushort8* s1 = (const ushort8*)(Wzb + p * 8192);
      #pragma unroll
      for (int i = 0; i < 4; ++i) d[tid + i * 256] = s1[tid + i * 256];
    }
    {
      ushort8* d2 = (ushort8*)sA2;
      const ushort8* sa = (const ushort8*)Wza;
      #pragma unroll
      for (int i = 0; i < 4; ++i) {
        int idx = tid + i * 256;
        int n = idx >> 3, q8 = idx & 7;
        d2[idx] = sa[n * 16 + p * 8 + q8];
      }
    }
    __syncthreads();

    f32x4 acc1[2][4] = {};
    #pragma unroll
    for (int ks = 0; ks < 4; ++ks) {
      const int kof = (ks * 32 + l4 * 8) ^ sw;
      #pragma unroll
      for (int nf = 0; nf < 4; ++nf) {
        short8 bh = *(const short8*)&sB[(nf * 16 + l15) * 128 + kof];
        #pragma unroll
        for (int mf = 0; mf < 2; ++mf)
          acc1[mf][nf] = __builtin_amdgcn_mfma_f32_16x16x32_bf16(BC(a[mf][ks]), BC(bh), acc1[mf][nf], 0, 0, 0);
      }
    }
    #pragma unroll
    for (int mf = 0; mf < 2; ++mf) {
      #pragma unroll
      for (int nf = 0; nf < 4; ++nf) {
        const int colL = nf * 16 + l15;
        const float bv = bb[p * 64 + colL];
        #pragma unroll
        for (int r = 0; r < 4; ++r) {
          const int rowL = wv * 32 + mf * 16 + l4 * 4 + r;
          sX[rowL * 64 + (colL ^ ((rowL & 7) << 3))] = f2bf(fmaxf(acc1[mf][nf][r] + bv, 0.f));
        }
      }
    }
    #pragma unroll
    for (int ks2 = 0; ks2 < 2; ++ks2) {
      const int xkof = (ks2 * 32 + l4 * 8) ^ sw;
      short8 xf[2];
      #pragma unroll
      for (int mf = 0; mf < 2; ++mf) {
        const int rowL = wv * 32 + mf * 16 + l15;
        xf[mf] = *(const short8*)&sX[rowL * 64 + xkof];
      }
      #pragma unroll
      for (int nf = 0; nf < 8; ++nf) {
        short8 wh = *(const short8*)&sA2[(nf * 16 + l15) * 64 + xkof];
        #pragma unroll
        for (int mf = 0; mf < 2; ++mf)
          acc2[mf][nf] = __builtin_amdgcn_mfma_f32_16x16x32_bf16(BC(xf[mf]), BC(wh), acc2[mf][nf], 0, 0, 0);
      }
    }
    __syncthreads();
  }
  #pragma unroll
  for (int mf = 0; mf < 2; ++mf) {
    #pragma unroll
    for (int n = 0; n < 8; ++n) {
      const int col = n * 16 + l15;
      #pragma unroll
      for (int r = 0; r < 4; ++r) {
        const int row = m0 + mf * 16 + l4 * 4 + r;
        if (row < NN) Yout[(size_t)row * HD + col] = f2bf(acc2[mf][n][r]);
      }
    }
  }
}

// ---------------- layer-4 GEMM + pool + final (done-counter) ----------
__global__ __launch_bounds__(256) void k_bpool(const unsigned short* __restrict__ H,
                                               const unsigned short* __restrict__ Wzb,
                                               const float* __restrict__ bb,
                                               const float* __restrict__ Wl,
                                               const int* __restrict__ batch,
                                               float* __restrict__ sums,
                                               float* __restrict__ cnts,
                                               const float* __restrict__ bl,
                                               float* __restrict__ outp,
                                               int* __restrict__ done) {
  __shared__ unsigned short sW[16384];  // 32 KB: Wb hi
  __shared__ float sb[NG];
  __shared__ int sc[NG];
  __shared__ int slast;
  const int tid = threadIdx.x;
  const int wv = tid >> 6, ln = tid & 63;
  const int l15 = ln & 15, l4 = ln >> 4;
  const int m0 = blockIdx.x * 128 + wv * 32;
  const int sw = (l15 & 7) << 3;
  for (int i = tid; i < NG; i += 256) { sb[i] = 0.f; sc[i] = 0; }
  {
    const ushort8* src = (const ushort8*)Wzb;
    ushort8* dst = (ushort8*)sW;
    #pragma unroll
    for (int i = 0; i < 8; ++i) dst[tid + i * 256] = src[tid + i * 256];
  }
  __syncthreads();
  f32x4 acc[2][8] = {};
  #pragma unroll
  for (int ks = 0; ks < 4; ++ks) {
    const int kbase = ks * 32 + l4 * 8;
    short8 a[2];
    #pragma unroll
    for (int mf = 0; mf < 2; ++mf) {
      const int row = m0 + mf * 16 + l15;
      if (row < NN) a[mf] = *(const short8*)(H + (size_t)row * HD + kbase);
      else a[mf] = short8{0, 0, 0, 0, 0, 0, 0, 0};
    }
    const int kof = (kbase ^ sw) + l15 * 128;
    #pragma unroll
    for (int n = 0; n < 8; ++n) {
      short8 bh = *(const short8*)&sW[n * 2048 + kof];
      #pragma unroll
      for (int mf = 0; mf < 2; ++mf)
        acc[mf][n] = __builtin_amdgcn_mfma_f32_16x16x32_bf16(BC(a[mf]), BC(bh), acc[mf][n], 0, 0, 0);
    }
  }
  float pdot[2][4] = {};
  #pragma unroll
  for (int mf = 0; mf < 2; ++mf) {
    #pragma unroll
    for (int n = 0; n < 8; ++n) {
      const int col = n * 16 + l15;
      const float bv = bb[col];
      const float wl = Wl[col];
      #pragma unroll
      for (int r = 0; r < 4; ++r)
        pdot[mf][r] += fmaxf(acc[mf][n][r] + bv, 0.f) * wl;
    }
  }
  #pragma unroll
  for (int mf = 0; mf < 2; ++mf) {
    #pragma unroll
    for (int r = 0; r < 4; ++r) {
      float d = pdot[mf][r];
      d += __shfl_xor(d, 1);
      d += __shfl_xor(d, 2);
      d += __shfl_xor(d, 4);
      d += __shfl_xor(d, 8);
      if (l15 == 0) {
        const int row = m0 + mf * 16 + l4 * 4 + r;
        if (row < NN) {
          const int g = batch[row];
          atomicAdd(&sb[g], d);
          atomicAdd(&sc[g], 1);
        }
      }
    }
  }
  __syncthreads();
  for (int i = tid; i < NG; i += 256)
    if (sc[i]) { atomicAdd(&sums[i], sb[i]); atomicAdd(&cnts[i], (float)sc[i]); }
  // completion: last block computes final output
  __syncthreads();
  __threadfence();
  if (tid == 0) slast = (atomicAdd(done, 1) == (int)gridDim.x - 1);
  __syncthreads();
  if (slast) {
    const float b0 = bl[0];
    for (int g = tid; g < NG; g += 256) {
      float s = atomicAdd(&sums[g], 0.f);   // coherent cross-XCD read
      float c = atomicAdd(&cnts[g], 0.f);
      outp[g] = s / fmaxf(c, 1.f) + b0;
    }
  }
}

// ---------------- launch ----------------
extern "C" void kernel_launch(void* const* d_in, const int* in_sizes, int n_in,
                              void* d_out, int out_size, void* d_ws, size_t ws_size,
                              hipStream_t stream) {
  const float* x = (const float*)d_in[0];
  const int* edges = (const int*)d_in[1];
  const int* batch = (const int*)d_in[2];
  const int* e_src = edges;
  const int* e_dst = edges + NE;
  const float* Wl = (const float*)d_in[35];
  const float* bl = (const float*)d_in[36];
  float* out = (float*)d_out;
  auto P = [&](int l, int which) -> const float* {
    return (const float*)d_in[3 + (l - 1) * 8 + which];
  };

  char* ws = (char*)d_ws;
  size_t off = 0;
  auto take = [&](size_t bytes) -> void* {
    void* p = ws + off;
    off = (off + bytes + 255) & ~(size_t)255;
    return p;
  };
  unsigned short* Y = (unsigned short*)take((size_t)NN * HD * 2);
  unsigned short* H = (unsigned short*)take((size_t)NN * HD * 2);
  int* row_ptr = (int*)take((size_t)(NN + 1) * 4);
  int* col_idx = (int*)take((size_t)NE * 4);
  unsigned* pairs = (unsigned*)take((size_t)NBUK * BCAP * 4);
  int* gcur = (int*)take((size_t)NBUK * 4);
  int* done = (int*)take(256);
  unsigned short* Wza[4];
  unsigned short* Wzb[4];
  Wza[0] = (unsigned short*)take((size_t)2 * 16384 * 2);
  for (int l = 1; l < 4; ++l) Wza[l] = (unsigned short*)take((size_t)16384 * 2);
  for (int l = 0; l < 4; ++l) Wzb[l] = (unsigned short*)take((size_t)16384 * 2);
  float* bf = (float*)take((size_t)4 * HD * 4);
  float* psum = (float*)take((size_t)NG * 4 * 2);
  float* pcnt = psum + NG;

  PrepArgs pa;
  for (int c = 0; c < 9; ++c) {
    if (c < 2) { pa.W[c] = P(1, 0); pa.g[c] = P(1, 2); pa.rv[c] = P(1, 5);
                 pa.out[c] = Wza[0] + c * 16384; pa.k0[c] = c * 128; pa.K[c] = FIN; }
    else if (c < 5) { int l = c - 1; pa.W[c] = P(l + 1, 0); pa.g[c] = P(l + 1, 2);
                      pa.rv[c] = P(l + 1, 5); pa.out[c] = Wza[l]; pa.k0[c] = 0; pa.K[c] = HD; }
    else { int l = c - 5; pa.W[c] = P(l + 1, 6); pa.g[c] = nullptr; pa.rv[c] = nullptr;
           pa.out[c] = Wzb[l]; pa.k0[c] = 0; pa.K[c] = HD; }
  }
  for (int l = 0; l < 4; ++l) {
    pa.ba[l] = P(l + 1, 1); pa.gg[l] = P(l + 1, 2); pa.be[l] = P(l + 1, 3);
    pa.rm[l] = P(l + 1, 4); pa.rvv[l] = P(l + 1, 5);
  }
  pa.bout = bf;
  k_prep<<<(9 * 16384 + 512 + 2 * NG + NBUK + 1 + 255) / 256, 256, 0, stream>>>(pa, gcur, psum, done);

  // fat: bucket scatter (391 blocks) || GEMM1 (782 blocks)
  k_b1<<<BKB + G1B, 256, 0, stream>>>(e_src, e_dst, gcur, pairs, x, Wza[0], Y);
  k_pass2<<<NBUK, 512, 0, stream>>>(pairs, gcur, row_ptr, col_idx);

  const int grid = (NN + 127) / 128;
  for (int l = 1; l <= 3; ++l) {
    k_agg<<<NN / 4, 256, 0, stream>>>(Y, row_ptr, col_idx, bf + (l - 1) * HD, H);
    k_fused<<<grid, 256, 0, stream>>>(H, Wzb[l - 1], P(l, 7), Wza[l], Y);
  }
  k_agg<<<NN / 4, 256, 0, stream>>>(Y, row_ptr, col_idx, bf + 3 * HD, H);
  k_bpool<<<grid, 256, 0, stream>>>(H, Wzb[3], P(4, 7), Wl, batch, psum, pcnt,
                                    bl, out, done);
}

// Round 12
// 443.227 us; speedup vs baseline: 1.1038x; 1.1038x over previous
//
#include <hip/hip_runtime.h>

#define NN 100000
#define NE 1600000
#define NG 512
#define FIN 226
#define HD 128
#define BN_EPS 1e-5f
#define NBUK 196        // ceil(NN/512)
#define BCAP 10016      // per-bucket pair capacity (mean 8163)
#define BKB 391         // bucket blocks = ceil(NE/4096)
#define G1B 782         // gemm1 blocks = ceil(NN/128)

typedef __attribute__((ext_vector_type(8))) __bf16 bf16x8;
typedef __attribute__((ext_vector_type(8))) short short8;
typedef __attribute__((ext_vector_type(8))) unsigned short ushort8;
typedef __attribute__((ext_vector_type(4))) float f32x4;
typedef __attribute__((ext_vector_type(2))) float f32x2;

#define BC(x) __builtin_bit_cast(bf16x8, x)

__device__ inline unsigned short f2bf(float v) {
  unsigned u = __builtin_bit_cast(unsigned, v);
  return (unsigned short)((u + 0x7FFFu + ((u >> 16) & 1u)) >> 16);
}
__device__ inline float bf2f(unsigned short b) {
  return __builtin_bit_cast(float, (unsigned)b << 16);
}

// ---------------- merged weight/bias prep + workspace zeroing ----------------
// all chunks swizzled: idx = n*128 + (kk ^ ((n&7)<<3))
struct PrepArgs {
  const float* W[9];
  const float* g[9];
  const float* rv[9];
  unsigned short* out[9];
  int k0[9];
  int K[9];
  const float* ba[4];
  const float* gg[4];
  const float* be[4];
  const float* rm[4];
  const float* rvv[4];
  float* bout;
};

__global__ __launch_bounds__(256) void k_prep(PrepArgs a, int* __restrict__ gcur,
                                              float* __restrict__ psum) {
  int id = blockIdx.x * 256 + threadIdx.x;
  if (id < 9 * 16384) {
    int chunk = id >> 14;
    int r = id & 16383;
    int kk = r >> 7;
    int n = r & 127;
    float s = a.g[chunk] ? a.g[chunk][n] * rsqrtf(a.rv[chunk][n] + BN_EPS) : 1.f;
    int kg = a.k0[chunk] + kk;
    float v = (kg < a.K[chunk]) ? a.W[chunk][(size_t)kg * HD + n] * s : 0.f;
    int idx = n * 128 + (kk ^ ((n & 7) << 3));
    a.out[chunk][idx] = f2bf(v);
  } else {
    int t = id - 9 * 16384;
    if (t < 512) {
      int l = t >> 7, c = t & 127;
      float s = a.gg[l][c] * rsqrtf(a.rvv[l][c] + BN_EPS);
      a.bout[l * 128 + c] = a.ba[l][c] * s + a.be[l][c] - a.rm[l][c] * s;
    } else if (t < 512 + 2 * NG) {
      psum[t - 512] = 0.f;
    } else if (t < 512 + 2 * NG + NBUK) {
      gcur[t - 512 - 2 * NG] = 0;
    }
  }
}

// ---------------- fat kernel: bucket scatter (blocks 0..390) | GEMM1 (blocks 391..1172)
__global__ __launch_bounds__(256) void k_b1(const int* __restrict__ src,
                                            const int* __restrict__ dst,
                                            int* __restrict__ gcur,
                                            unsigned* __restrict__ pairs,
                                            const float* __restrict__ A,
                                            const unsigned short* __restrict__ Wz,
                                            unsigned short* __restrict__ out) {
  __shared__ __align__(16) char smem[36096];
  const int tid = threadIdx.x;
  if (blockIdx.x < BKB) {
    // ======== bucket body ========
    int* sd = (int*)smem;                       // 16 KB
    int* ss = (int*)(smem + 16384);             // 16 KB
    int* sh = (int*)(smem + 32768);             // 196
    int* sexcl = sh + NBUK;
    int* scur = sexcl + NBUK;
    int* sbase = scur + NBUK;
    int* wsum = sbase + NBUK;                   // 4
    const int i0 = blockIdx.x * 4096;
    #pragma unroll
    for (int j = 0; j < 16; ++j) {
      int e = i0 + j * 256 + tid;
      sd[j * 256 + tid] = (e < NE) ? __builtin_nontemporal_load(dst + e) : -1;
      ss[j * 256 + tid] = (e < NE) ? __builtin_nontemporal_load(src + e) : 0;
    }
    if (tid < NBUK) sh[tid] = 0;
    __syncthreads();
    #pragma unroll
    for (int j = 0; j < 16; ++j) {
      int d = sd[j * 256 + tid];
      if (d >= 0) atomicAdd(&sh[d >> 9], 1);
    }
    __syncthreads();
    {
      int v = (tid < NBUK) ? sh[tid] : 0;
      int lane = tid & 63, w = tid >> 6;
      int incl = v;
      #pragma unroll
      for (int o = 1; o < 64; o <<= 1) {
        int u = __shfl_up(incl, o);
        if (lane >= o) incl += u;
      }
      if (lane == 63) wsum[w] = incl;
      __syncthreads();
      int off = 0;
      for (int k = 0; k < w; ++k) off += wsum[k];
      if (tid < NBUK) {
        int ex = off + incl - v;
        sexcl[tid] = ex;
        scur[tid] = ex;
        sbase[tid] = (v > 0) ? atomicAdd(&gcur[tid], v) : 0;
      }
    }
    __syncthreads();
    #pragma unroll
    for (int j = 0; j < 16; ++j) {
      int d = sd[j * 256 + tid];
      if (d >= 0) {
        int b = d >> 9;
        int lp = atomicAdd(&scur[b], 1);
        unsigned pk = ((unsigned)(d & 511) << 17) | (unsigned)ss[j * 256 + tid];
        pairs[(size_t)b * BCAP + sbase[b] + (lp - sexcl[b])] = pk;
      }
    }
  } else {
    // ======== GEMM1 body: f32 A hi+lo split @ bf16 W1a (2 chunks, K=226) ========
    unsigned short* sW = (unsigned short*)smem;  // 32 KB
    const int wv = tid >> 6, ln = tid & 63;
    const int l15 = ln & 15, l4 = ln >> 4;
    const int m0 = (blockIdx.x - BKB) * 128 + wv * 32;
    f32x4 acc[2][8] = {};
    const int sw = (l15 & 7) << 3;
    int kofs[4];
    #pragma unroll
    for (int ks = 0; ks < 4; ++ks) kofs[ks] = (((ks * 32 + l4 * 8) ^ sw)) + l15 * 128;

    for (int c = 0; c < 2; ++c) {
      {
        const ushort8* srcw = (const ushort8*)(Wz + (size_t)c * 16384);
        ushort8* dstw = (ushort8*)sW;
        #pragma unroll
        for (int i = 0; i < 8; ++i) dstw[tid + i * 256] = srcw[tid + i * 256];
      }
      __syncthreads();
      const int kc = c * 128;
      #pragma unroll
      for (int ks = 0; ks < 4; ++ks) {
        const int kbase = kc + ks * 32 + l4 * 8;
        const bool tail = (kc + ks * 32 + 32) > FIN;
        short8 ah[2], al[2];
        #pragma unroll
        for (int mf = 0; mf < 2; ++mf) {
          const int row = m0 + mf * 16 + l15;
          float v[8];
          if (row < NN && !tail) {
            const f32x2* ap = (const f32x2*)(A + (size_t)row * FIN + kbase);
            #pragma unroll
            for (int q = 0; q < 4; ++q) {
              f32x2 t = __builtin_nontemporal_load(ap + q);
              v[2 * q] = t[0]; v[2 * q + 1] = t[1];
            }
          } else if (row < NN) {
            #pragma unroll
            for (int j = 0; j < 8; ++j) {
              int k = kbase + j;
              v[j] = (k < FIN) ? A[(size_t)row * FIN + k] : 0.f;
            }
          } else {
            #pragma unroll
            for (int j = 0; j < 8; ++j) v[j] = 0.f;
          }
          #pragma unroll
          for (int j = 0; j < 8; ++j) {
            unsigned short hb = f2bf(v[j]);
            ah[mf][j] = (short)hb;
            al[mf][j] = (short)f2bf(v[j] - bf2f(hb));
          }
        }
        #pragma unroll
        for (int n = 0; n < 8; ++n) {
          short8 bh = *(const short8*)&sW[n * 2048 + kofs[ks]];
          #pragma unroll
          for (int mf = 0; mf < 2; ++mf) {
            acc[mf][n] = __builtin_amdgcn_mfma_f32_16x16x32_bf16(BC(ah[mf]), BC(bh), acc[mf][n], 0, 0, 0);
            acc[mf][n] = __builtin_amdgcn_mfma_f32_16x16x32_bf16(BC(al[mf]), BC(bh), acc[mf][n], 0, 0, 0);
          }
        }
      }
      __syncthreads();
    }
    #pragma unroll
    for (int mf = 0; mf < 2; ++mf) {
      #pragma unroll
      for (int n = 0; n < 8; ++n) {
        const int col = n * 16 + l15;
        #pragma unroll
        for (int r = 0; r < 4; ++r) {
          const int row = m0 + mf * 16 + l4 * 4 + r;
          if (row < NN) out[(size_t)row * HD + col] = f2bf(acc[mf][n][r]);
        }
      }
    }
  }
}

// pass 2: per-bucket local CSR in LDS; col_idx stored as ROW BYTE OFFSET (src*256)
__global__ __launch_bounds__(256) void k_pass2(const unsigned* __restrict__ pairs,
                                               const int* __restrict__ gcur,
                                               int* __restrict__ row_ptr,
                                               int* __restrict__ col_idx) {
  __shared__ unsigned spk[BCAP];
  __shared__ int h[512];
  __shared__ int cur[512];
  __shared__ int wsum[4];
  __shared__ int s_base;
  const int b = blockIdx.x;
  const int tid = threadIdx.x;
  {
    int v = (tid < NBUK) ? gcur[tid] : 0;
    int lane = tid & 63, w = tid >> 6;
    int incl = v;
    #pragma unroll
    for (int o = 1; o < 64; o <<= 1) {
      int u = __shfl_up(incl, o);
      if (lane >= o) incl += u;
    }
    if (lane == 63) wsum[w] = incl;
    __syncthreads();
    int off = 0;
    for (int k = 0; k < w; ++k) off += wsum[k];
    if (tid == b) s_base = off + incl - v;
    if (b == 0 && tid == 0) row_ptr[NN] = NE;
  }
  const int cnt = gcur[b];
  __syncthreads();
  const int base = s_base;
  for (int i = tid; i < cnt; i += 256) spk[i] = pairs[(size_t)b * BCAP + i];
  h[tid] = 0; h[tid + 256] = 0;
  __syncthreads();
  for (int i = tid; i < cnt; i += 256) atomicAdd(&h[spk[i] >> 17], 1);
  __syncthreads();
  int c0 = h[2 * tid], c1 = h[2 * tid + 1];
  {
    int v = c0 + c1;
    int lane = tid & 63, w = tid >> 6;
    int incl = v;
    #pragma unroll
    for (int o = 1; o < 64; o <<= 1) {
      int u = __shfl_up(incl, o);
      if (lane >= o) incl += u;
    }
    if (lane == 63) wsum[w] = incl;
    __syncthreads();
    int off = 0;
    for (int k = 0; k < w; ++k) off += wsum[k];
    int e0 = off + incl - v;
    int e1 = e0 + c0;
    int node0 = b * 512 + 2 * tid;
    if (node0 < NN) row_ptr[node0] = base + e0;
    if (node0 + 1 < NN) row_ptr[node0 + 1] = base + e1;
    cur[2 * tid] = e0;
    cur[2 * tid + 1] = e1;
  }
  __syncthreads();
  for (int i = tid; i < cnt; i += 256) {
    unsigned pk = spk[i];
    int dl = pk >> 17;
    int p = atomicAdd(&cur[dl], 1);
    col_idx[base + p] = (int)((pk & 0x1FFFFu) << 8);  // row byte offset (HD*2 = 256)
  }
}

// ---------------- aggregation (bf16): col_idx holds byte offsets ----------
__global__ __launch_bounds__(256) void k_agg(const unsigned short* __restrict__ y,
                                             const int* __restrict__ row_ptr,
                                             const int* __restrict__ col_idx,
                                             const float* __restrict__ bias,
                                             unsigned short* __restrict__ h) {
  const int node = blockIdx.x * 4 + (threadIdx.x >> 6);
  const int ln = threadIdx.x & 63;
  const int l15 = ln & 15, grp = ln >> 4;
  if (node >= NN) return;
  const char* yb = (const char*)y;
  const int lo = l15 * 16;
  float acc[8] = {};
  const int beg = row_ptr[node], end = row_ptr[node + 1];
  int e = beg;
  for (; e + 16 <= end; e += 16) {
    const int s0 = __builtin_nontemporal_load(col_idx + e + grp);
    const int s1 = __builtin_nontemporal_load(col_idx + e + 4 + grp);
    const int s2 = __builtin_nontemporal_load(col_idx + e + 8 + grp);
    const int s3 = __builtin_nontemporal_load(col_idx + e + 12 + grp);
    const ushort8 v0 = *(const ushort8*)(yb + s0 + lo);
    const ushort8 v1 = *(const ushort8*)(yb + s1 + lo);
    const ushort8 v2 = *(const ushort8*)(yb + s2 + lo);
    const ushort8 v3 = *(const ushort8*)(yb + s3 + lo);
    #pragma unroll
    for (int j = 0; j < 8; ++j)
      acc[j] += (bf2f((unsigned short)v0[j]) + bf2f((unsigned short)v1[j])) +
                (bf2f((unsigned short)v2[j]) + bf2f((unsigned short)v3[j]));
  }
  for (; e + 8 <= end; e += 8) {
    const int s0 = __builtin_nontemporal_load(col_idx + e + grp);
    const int s1 = __builtin_nontemporal_load(col_idx + e + 4 + grp);
    const ushort8 v0 = *(const ushort8*)(yb + s0 + lo);
    const ushort8 v1 = *(const ushort8*)(yb + s1 + lo);
    #pragma unroll
    for (int j = 0; j < 8; ++j)
      acc[j] += bf2f((unsigned short)v0[j]) + bf2f((unsigned short)v1[j]);
  }
  if (e + 4 <= end) {
    const int s0 = __builtin_nontemporal_load(col_idx + e + grp);
    const ushort8 v0 = *(const ushort8*)(yb + s0 + lo);
    #pragma unroll
    for (int j = 0; j < 8; ++j) acc[j] += bf2f((unsigned short)v0[j]);
    e += 4;
  }
  if (e + grp < end) {
    const int s0 = col_idx[e + grp];
    const ushort8 v0 = *(const ushort8*)(yb + s0 + lo);
    #pragma unroll
    for (int j = 0; j < 8; ++j) acc[j] += bf2f((unsigned short)v0[j]);
  }
  #pragma unroll
  for (int j = 0; j < 8; ++j) {
    acc[j] += __shfl_xor(acc[j], 16);
    acc[j] += __shfl_xor(acc[j], 32);
  }
  const ushort8 sv = *(const ushort8*)(y + (size_t)node * HD + l15 * 8);
  const f32x4* b4 = (const f32x4*)(bias + l15 * 8);
  const f32x4 b0 = b4[0], b1 = b4[1];
  ushort8 o;
  #pragma unroll
  for (int j = 0; j < 8; ++j) {
    const float bj = (j < 4) ? b0[j] : b1[j - 4];
    o[j] = (unsigned short)f2bf(fmaxf(acc[j] + bf2f((unsigned short)sv[j]) + bj, 0.f));
  }
  if (grp == 0) *(ushort8*)(h + (size_t)node * HD + l15 * 8) = o;
}

// ---------------- fused Wb+Wa GEMM (bf16 weights): Y = relu(H@Wb + bb) @ Wa ----------
__global__ __launch_bounds__(256) void k_fused(const unsigned short* __restrict__ H,
                                               const unsigned short* __restrict__ Wzb,
                                               const float* __restrict__ bb,
                                               const unsigned short* __restrict__ Wza,
                                               unsigned short* __restrict__ Yout) {
  __shared__ __align__(16) char smem[49152];
  unsigned short* sB = (unsigned short*)smem;            // 16 KB: Wb N-half
  unsigned short* sA2 = (unsigned short*)(smem + 16384); // 16 KB: Wa k-half
  unsigned short* sX = (unsigned short*)(smem + 32768);  // 16 KB: X half-tile swizzled
  const int tid = threadIdx.x;
  const int wv = tid >> 6, ln = tid & 63;
  const int l15 = ln & 15, l4 = ln >> 4;
  const int m0 = blockIdx.x * 128 + wv * 32;
  const int sw = (l15 & 7) << 3;
  f32x4 acc2[2][8] = {};

  short8 a[2][4];
  #pragma unroll
  for (int mf = 0; mf < 2; ++mf) {
    const int row = m0 + mf * 16 + l15;
    #pragma unroll
    for (int ks = 0; ks < 4; ++ks) {
      if (row < NN) a[mf][ks] = *(const short8*)(H + (size_t)row * HD + ks * 32 + l4 * 8);
      else a[mf][ks] = short8{0, 0, 0, 0, 0, 0, 0, 0};
    }
  }

  #pragma unroll 1
  for (int p = 0; p < 2; ++p) {
    {
      ushort8* d = (ushort8*)sB;
      const ushort8* s1 = (const ushort8*)(Wzb + p * 8192);
      #pragma unroll
      for (int i = 0; i < 4; ++i) d[tid + i * 256] = s1[tid + i * 256];
    }
    {
      ushort8* d2 = (ushort8*)sA2;
      const ushort8* sa = (const ushort8*)Wza;
      #pragma unroll
      for (int i = 0; i < 4; ++i) {
        int idx = tid + i * 256;
        int n = idx >> 3, q8 = idx & 7;
        d2[idx] = sa[n * 16 + p * 8 + q8];
      }
    }
    __syncthreads();

    f32x4 acc1[2][4] = {};
    #pragma unroll
    for (int ks = 0; ks < 4; ++ks) {
      const int kof = (ks * 32 + l4 * 8) ^ sw;
      #pragma unroll
      for (int nf = 0; nf < 4; ++nf) {
        short8 bh = *(const short8*)&sB[(nf * 16 + l15) * 128 + kof];
        #pragma unroll
        for (int mf = 0; mf < 2; ++mf)
          acc1[mf][nf] = __builtin_amdgcn_mfma_f32_16x16x32_bf16(BC(a[mf][ks]), BC(bh), acc1[mf][nf], 0, 0, 0);
      }
    }
    #pragma unroll
    for (int mf = 0; mf < 2; ++mf) {
      #pragma unroll
      for (int nf = 0; nf < 4; ++nf) {
        const int colL = nf * 16 + l15;
        const float bv = bb[p * 64 + colL];
        #pragma unroll
        for (int r = 0; r < 4; ++r) {
          const int rowL = wv * 32 + mf * 16 + l4 * 4 + r;
          sX[rowL * 64 + (colL ^ ((rowL & 7) << 3))] = f2bf(fmaxf(acc1[mf][nf][r] + bv, 0.f));
        }
      }
    }
    #pragma unroll
    for (int ks2 = 0; ks2 < 2; ++ks2) {
      const int xkof = (ks2 * 32 + l4 * 8) ^ sw;
      short8 xf[2];
      #pragma unroll
      for (int mf = 0; mf < 2; ++mf) {
        const int rowL = wv * 32 + mf * 16 + l15;
        xf[mf] = *(const short8*)&sX[rowL * 64 + xkof];
      }
      #pragma unroll
      for (int nf = 0; nf < 8; ++nf) {
        short8 wh = *(const short8*)&sA2[(nf * 16 + l15) * 64 + xkof];
        #pragma unroll
        for (int mf = 0; mf < 2; ++mf)
          acc2[mf][nf] = __builtin_amdgcn_mfma_f32_16x16x32_bf16(BC(xf[mf]), BC(wh), acc2[mf][nf], 0, 0, 0);
      }
    }
    __syncthreads();
  }
  #pragma unroll
  for (int mf = 0; mf < 2; ++mf) {
    #pragma unroll
    for (int n = 0; n < 8; ++n) {
      const int col = n * 16 + l15;
      #pragma unroll
      for (int r = 0; r < 4; ++r) {
        const int row = m0 + mf * 16 + l4 * 4 + r;
        if (row < NN) Yout[(size_t)row * HD + col] = f2bf(acc2[mf][n][r]);
      }
    }
  }
}

// ---------------- layer-4 GEMM + pool ----------
__global__ __launch_bounds__(256) void k_bpool(const unsigned short* __restrict__ H,
                                               const unsigned short* __restrict__ Wzb,
                                               const float* __restrict__ bb,
                                               const float* __restrict__ Wl,
                                               const int* __restrict__ batch,
                                               float* __restrict__ sums,
                                               float* __restrict__ cnts) {
  __shared__ unsigned short sW[16384];  // 32 KB: Wb hi
  __shared__ float sb[NG];
  __shared__ int sc[NG];
  const int tid = threadIdx.x;
  const int wv = tid >> 6, ln = tid & 63;
  const int l15 = ln & 15, l4 = ln >> 4;
  const int m0 = blockIdx.x * 128 + wv * 32;
  const int sw = (l15 & 7) << 3;
  for (int i = tid; i < NG; i += 256) { sb[i] = 0.f; sc[i] = 0; }
  {
    const ushort8* src = (const ushort8*)Wzb;
    ushort8* dst = (ushort8*)sW;
    #pragma unroll
    for (int i = 0; i < 8; ++i) dst[tid + i * 256] = src[tid + i * 256];
  }
  __syncthreads();
  f32x4 acc[2][8] = {};
  #pragma unroll
  for (int ks = 0; ks < 4; ++ks) {
    const int kbase = ks * 32 + l4 * 8;
    short8 a[2];
    #pragma unroll
    for (int mf = 0; mf < 2; ++mf) {
      const int row = m0 + mf * 16 + l15;
      if (row < NN) a[mf] = *(const short8*)(H + (size_t)row * HD + kbase);
      else a[mf] = short8{0, 0, 0, 0, 0, 0, 0, 0};
    }
    const int kof = (kbase ^ sw) + l15 * 128;
    #pragma unroll
    for (int n = 0; n < 8; ++n) {
      short8 bh = *(const short8*)&sW[n * 2048 + kof];
      #pragma unroll
      for (int mf = 0; mf < 2; ++mf)
        acc[mf][n] = __builtin_amdgcn_mfma_f32_16x16x32_bf16(BC(a[mf]), BC(bh), acc[mf][n], 0, 0, 0);
    }
  }
  float pdot[2][4] = {};
  #pragma unroll
  for (int mf = 0; mf < 2; ++mf) {
    #pragma unroll
    for (int n = 0; n < 8; ++n) {
      const int col = n * 16 + l15;
      const float bv = bb[col];
      const float wl = Wl[col];
      #pragma unroll
      for (int r = 0; r < 4; ++r)
        pdot[mf][r] += fmaxf(acc[mf][n][r] + bv, 0.f) * wl;
    }
  }
  #pragma unroll
  for (int mf = 0; mf < 2; ++mf) {
    #pragma unroll
    for (int r = 0; r < 4; ++r) {
      float d = pdot[mf][r];
      d += __shfl_xor(d, 1);
      d += __shfl_xor(d, 2);
      d += __shfl_xor(d, 4);
      d += __shfl_xor(d, 8);
      if (l15 == 0) {
        const int row = m0 + mf * 16 + l4 * 4 + r;
        if (row < NN) {
          const int g = batch[row];
          atomicAdd(&sb[g], d);
          atomicAdd(&sc[g], 1);
        }
      }
    }
  }
  __syncthreads();
  for (int i = tid; i < NG; i += 256)
    if (sc[i]) { atomicAdd(&sums[i], sb[i]); atomicAdd(&cnts[i], (float)sc[i]); }
}

__global__ void k_final(const float* __restrict__ sums, const float* __restrict__ cnts,
                        const float* __restrict__ bl, float* __restrict__ out) {
  int g = blockIdx.x * 256 + threadIdx.x;
  if (g < NG) out[g] = sums[g] / fmaxf(cnts[g], 1.f) + bl[0];
}

// ---------------- launch ----------------
extern "C" void kernel_launch(void* const* d_in, const int* in_sizes, int n_in,
                              void* d_out, int out_size, void* d_ws, size_t ws_size,
                              hipStream_t stream) {
  const float* x = (const float*)d_in[0];
  const int* edges = (const int*)d_in[1];
  const int* batch = (const int*)d_in[2];
  const int* e_src = edges;
  const int* e_dst = edges + NE;
  const float* Wl = (const float*)d_in[35];
  const float* bl = (const float*)d_in[36];
  float* out = (float*)d_out;
  auto P = [&](int l, int which) -> const float* {
    return (const float*)d_in[3 + (l - 1) * 8 + which];
  };

  char* ws = (char*)d_ws;
  size_t off = 0;
  auto take = [&](size_t bytes) -> void* {
    void* p = ws + off;
    off = (off + bytes + 255) & ~(size_t)255;
    return p;
  };
  unsigned short* Y = (unsigned short*)take((size_t)NN * HD * 2);
  unsigned short* H = (unsigned short*)take((size_t)NN * HD * 2);
  int* row_ptr = (int*)take((size_t)(NN + 1) * 4);
  int* col_idx = (int*)take((size_t)NE * 4);
  unsigned* pairs = (unsigned*)take((size_t)NBUK * BCAP * 4);
  int* gcur = (int*)take((size_t)NBUK * 4);
  unsigned short* Wza[4];
  unsigned short* Wzb[4];
  Wza[0] = (unsigned short*)take((size_t)2 * 16384 * 2);
  for (int l = 1; l < 4; ++l) Wza[l] = (unsigned short*)take((size_t)16384 * 2);
  for (int l = 0; l < 4; ++l) Wzb[l] = (unsigned short*)take((size_t)16384 * 2);
  float* bf = (float*)take((size_t)4 * HD * 4);
  float* psum = (float*)take((size_t)NG * 4 * 2);
  float* pcnt = psum + NG;

  // prep (weights + biases + zero gcur/psum) — must run before k_b1
  PrepArgs pa;
  for (int c = 0; c < 9; ++c) {
    if (c < 2) { pa.W[c] = P(1, 0); pa.g[c] = P(1, 2); pa.rv[c] = P(1, 5);
                 pa.out[c] = Wza[0] + c * 16384; pa.k0[c] = c * 128; pa.K[c] = FIN; }
    else if (c < 5) { int l = c - 1; pa.W[c] = P(l + 1, 0); pa.g[c] = P(l + 1, 2);
                      pa.rv[c] = P(l + 1, 5); pa.out[c] = Wza[l]; pa.k0[c] = 0; pa.K[c] = HD; }
    else { int l = c - 5; pa.W[c] = P(l + 1, 6); pa.g[c] = nullptr; pa.rv[c] = nullptr;
           pa.out[c] = Wzb[l]; pa.k0[c] = 0; pa.K[c] = HD; }
  }
  for (int l = 0; l < 4; ++l) {
    pa.ba[l] = P(l + 1, 1); pa.gg[l] = P(l + 1, 2); pa.be[l] = P(l + 1, 3);
    pa.rm[l] = P(l + 1, 4); pa.rvv[l] = P(l + 1, 5);
  }
  pa.bout = bf;
  k_prep<<<(9 * 16384 + 512 + 2 * NG + NBUK + 255) / 256, 256, 0, stream>>>(pa, gcur, psum);

  // fat: bucket scatter (391 blocks) || GEMM1 (782 blocks)
  k_b1<<<BKB + G1B, 256, 0, stream>>>(e_src, e_dst, gcur, pairs, x, Wza[0], Y);
  k_pass2<<<NBUK, 256, 0, stream>>>(pairs, gcur, row_ptr, col_idx);

  const int grid = (NN + 127) / 128;
  for (int l = 1; l <= 3; ++l) {
    k_agg<<<NN / 4, 256, 0, stream>>>(Y, row_ptr, col_idx, bf + (l - 1) * HD, H);
    k_fused<<<grid, 256, 0, stream>>>(H, Wzb[l - 1], P(l, 7), Wza[l], Y);
  }
  k_agg<<<NN / 4, 256, 0, stream>>>(Y, row_ptr, col_idx, bf + 3 * HD, H);
  k_bpool<<<grid, 256, 0, stream>>>(H, Wzb[3], P(4, 7), Wl, batch, psum, pcnt);
  k_final<<<(NG + 255) / 256, 256, 0, stream>>>(psum, pcnt, bl, out);
}